// Round 3
// baseline (711.612 us; speedup 1.0000x reference)
//
#include <hip/hip_runtime.h>
#include <hip/hip_bf16.h>

// All reference dtypes are float32 (per setup_inputs): inputs const float*,
// output float*.

#define BATCH 2
#define NTOK 9216        // 96*96
#define CCH 64
#define DK 8
#define DV 32
#define KS 16            // key splits
#define KEYS_PER_SPLIT (NTOK / KS)   // 576
#define BK 64            // keys per LDS tile
#define TILES (KEYS_PER_SPLIT / BK)  // 9
#define NQB (NTOK / 256)             // 36 query-blocks per (batch, split)
#define LOG2E 1.44269504088896340736f

#define ROWS (BATCH * NTOK)          // 18432

// ---------------------------------------------------------------------------
// Kernel 0: zero the accumulator region (l_acc + o_acc).
// (18432 + 589824) floats = 608256 floats = 152064 float4.
// ---------------------------------------------------------------------------
__global__ __launch_bounds__(256) void zero_kernel(float4* __restrict__ p) {
    int i = blockIdx.x * 256 + threadIdx.x;
    if (i < 152064) p[i] = make_float4(0.f, 0.f, 0.f, 0.f);
}

// ---------------------------------------------------------------------------
// Kernel 1: projections. f = x@W1+b1 ; g = (x@W2+b2)*log2e ; h = x@W3+b3
// One thread per output element (row, col) with col in [0,48): 8 f, 8 g, 32 h.
// ---------------------------------------------------------------------------
__global__ __launch_bounds__(256) void proj_kernel(
    const float* __restrict__ x,
    const float* __restrict__ W1, const float* __restrict__ b1,
    const float* __restrict__ W2, const float* __restrict__ b2,
    const float* __restrict__ W3, const float* __restrict__ b3,
    float* __restrict__ f, float* __restrict__ g, float* __restrict__ h)
{
    int idx = blockIdx.x * 256 + threadIdx.x;   // < 18432*48 exactly
    int row = idx / 48;
    int col = idx - row * 48;
    const float* xr = x + (size_t)row * CCH;
    if (col < 8) {
        float acc = b1[col];
        #pragma unroll
        for (int k = 0; k < CCH; ++k) acc += xr[k] * W1[k * 8 + col];
        f[row * 8 + col] = acc;
    } else if (col < 16) {
        int c = col - 8;
        float acc = b2[c];
        #pragma unroll
        for (int k = 0; k < CCH; ++k) acc += xr[k] * W2[k * 8 + c];
        g[row * 8 + c] = acc * LOG2E;           // fold log2(e) for exp2 inner loop
    } else {
        int c = col - 16;
        float acc = b3[c];
        #pragma unroll
        for (int k = 0; k < CCH; ++k) acc += xr[k] * W3[k * 32 + c];
        h[row * 32 + c] = acc;
    }
}

// ---------------------------------------------------------------------------
// Kernel 2: flash-style attention partials, no online max (scores bounded:
// |s|*log2e <~ 25, exp2 cannot overflow fp32; l,acc << fp32 max).
// No per-split max shift -> split partials are directly summable -> merge via
// fp32 atomicAdd into l_acc / o_acc (6 MB total ws, no giant partial buffer).
// Grid: BATCH * KS * NQB blocks, 256 threads; thread t owns query qb*256+t.
// ---------------------------------------------------------------------------
__global__ __launch_bounds__(256) void attn_partial_kernel(
    const float* __restrict__ f, const float* __restrict__ g,
    const float* __restrict__ h,
    float* __restrict__ l_acc, float* __restrict__ o_acc)
{
    __shared__ float fT[BK * DK];   // 512 floats
    __shared__ float hT[BK * DV];   // 2048 floats

    int blk = blockIdx.x;
    int b   = blk / (KS * NQB);
    int rem = blk - b * (KS * NQB);
    int ks  = rem / NQB;
    int qb  = rem - ks * NQB;
    int q   = qb * 256 + threadIdx.x;
    int row = b * NTOK + q;

    const float4* gp4 = (const float4*)(g + (size_t)row * 8);
    float4 ga = gp4[0];
    float4 gb = gp4[1];

    float l = 0.f;
    float acc[DV];
    #pragma unroll
    for (int k = 0; k < DV; ++k) acc[k] = 0.f;

    int k0 = ks * KEYS_PER_SPLIT;
    for (int t = 0; t < TILES; ++t) {
        int kbase = b * NTOK + k0 + t * BK;
        const float4* fsrc = (const float4*)(f + (size_t)kbase * 8);
        const float4* hsrc = (const float4*)(h + (size_t)kbase * 32);
        int tid = threadIdx.x;
        if (tid < 128) ((float4*)fT)[tid] = fsrc[tid];          // 128 float4
        ((float4*)hT)[tid]       = hsrc[tid];                   // 512 float4
        ((float4*)hT)[tid + 256] = hsrc[tid + 256];
        __syncthreads();

        #pragma unroll 4
        for (int j = 0; j < BK; ++j) {
            const float4* fj = (const float4*)(fT + j * DK);    // broadcast reads
            float4 fa = fj[0], fb = fj[1];
            float s = ga.x * fa.x + ga.y * fa.y + ga.z * fa.z + ga.w * fa.w
                    + gb.x * fb.x + gb.y * fb.y + gb.z * fb.z + gb.w * fb.w;
            float p = exp2f(s);
            l += p;
            const float4* hj = (const float4*)(hT + j * DV);    // broadcast reads
            #pragma unroll
            for (int kk = 0; kk < 8; ++kk) {
                float4 hv = hj[kk];
                acc[4 * kk + 0] += p * hv.x;
                acc[4 * kk + 1] += p * hv.y;
                acc[4 * kk + 2] += p * hv.z;
                acc[4 * kk + 3] += p * hv.w;
            }
        }
        __syncthreads();
    }

    atomicAdd(&l_acc[row], l);
    float* oa = o_acc + (size_t)row * DV;
    #pragma unroll
    for (int k = 0; k < DV; ++k) atomicAdd(&oa[k], acc[k]);
}

// ---------------------------------------------------------------------------
// Kernel 3: normalize + output projection + residual.
// One wave per query (4 waves / 256-thread block).
//   o[k] = o_acc[row][k] / l_acc[row] ; out = gamma*(o@W4 + b4) + x
// ---------------------------------------------------------------------------
__global__ __launch_bounds__(256) void merge_kernel(
    const float* __restrict__ l_acc, const float* __restrict__ o_acc,
    const float* __restrict__ x,
    const float* __restrict__ W4, const float* __restrict__ b4,
    const float* __restrict__ gamma, float* __restrict__ out)
{
    __shared__ float oS[4][DV];
    int wave = threadIdx.x >> 6;
    int lane = threadIdx.x & 63;
    int row  = blockIdx.x * 4 + wave;     // < 18432 exactly

    float invL = 1.f / l_acc[row];
    if (lane < DV) {
        oS[wave][lane] = o_acc[(size_t)row * DV + lane] * invL;
    }
    __syncthreads();

    float dot = b4[lane];
    #pragma unroll
    for (int k = 0; k < DV; ++k) dot += oS[wave][k] * W4[k * 64 + lane];
    float gm  = gamma[0];
    float res = x[(size_t)row * 64 + lane];
    out[(size_t)row * 64 + lane] = gm * dot + res;
}

// ---------------------------------------------------------------------------
extern "C" void kernel_launch(void* const* d_in, const int* in_sizes, int n_in,
                              void* d_out, int out_size, void* d_ws, size_t ws_size,
                              hipStream_t stream) {
    const float* x     = (const float*)d_in[0];
    const float* W1    = (const float*)d_in[1];
    const float* b1    = (const float*)d_in[2];
    const float* W2    = (const float*)d_in[3];
    const float* b2    = (const float*)d_in[4];
    const float* W3    = (const float*)d_in[5];
    const float* b3    = (const float*)d_in[6];
    const float* W4    = (const float*)d_in[7];
    const float* b4    = (const float*)d_in[8];
    const float* gamma = (const float*)d_in[9];
    float* out = (float*)d_out;

    // Workspace layout (floats): total 1,492,992 floats = 5.97 MB
    float* ws = (float*)d_ws;
    float* f     = ws;                        // [0,       147456)
    float* g     = ws + 147456;               // [147456,  294912)
    float* h     = ws + 294912;               // [294912,  884736)
    float* l_acc = ws + 884736;               // [884736,  903168)
    float* o_acc = ws + 903168;               // [903168, 1492992)

    // zero l_acc + o_acc: 608256 floats = 152064 float4 -> 594 blocks
    zero_kernel<<<594, 256, 0, stream>>>((float4*)l_acc);

    // proj: 18432*48 threads
    proj_kernel<<<(ROWS * 48) / 256, 256, 0, stream>>>(
        x, W1, b1, W2, b2, W3, b3, f, g, h);

    // attention partials: 2*16*36 = 1152 blocks
    attn_partial_kernel<<<BATCH * KS * NQB, 256, 0, stream>>>(f, g, h, l_acc, o_acc);

    // merge: 18432 queries / 4 waves per block
    merge_kernel<<<ROWS / 4, 256, 0, stream>>>(l_acc, o_acc, x, W4, b4, gamma, out);
}

// Round 4
// 615.692 us; speedup vs baseline: 1.1558x; 1.1558x over previous
//
#include <hip/hip_runtime.h>
#include <hip/hip_bf16.h>

// All reference dtypes are float32 (verified R3): inputs const float*, output float*.

#define BATCH 2
#define NTOK 9216        // 96*96
#define CCH 64
#define DK 8
#define DV 32
#define KS 8                          // key splits (blocks per query-group)
#define KEYS_PER_BLOCK (NTOK / KS)    // 1152
#define KEYS_PER_WAVE (KEYS_PER_BLOCK / 4)  // 288
#define QG 144                        // query groups (ROWS/128)
#define LOG2E 1.44269504088896340736f

#define ROWS (BATCH * NTOK)          // 18432

// ---------------------------------------------------------------------------
// Kernel 0: zero the accumulator region (l_acc + o_acc).
// (18432 + 589824) floats = 608256 floats = 152064 float4.
// ---------------------------------------------------------------------------
__global__ __launch_bounds__(256) void zero_kernel(float4* __restrict__ p) {
    int i = blockIdx.x * 256 + threadIdx.x;
    if (i < 152064) p[i] = make_float4(0.f, 0.f, 0.f, 0.f);
}

// ---------------------------------------------------------------------------
// Kernel 1: projections. f = x@W1+b1 ; g = (x@W2+b2)*log2e ; h = x@W3+b3
// One thread per output element (row, col) with col in [0,48): 8 f, 8 g, 32 h.
// ---------------------------------------------------------------------------
__global__ __launch_bounds__(256) void proj_kernel(
    const float* __restrict__ x,
    const float* __restrict__ W1, const float* __restrict__ b1,
    const float* __restrict__ W2, const float* __restrict__ b2,
    const float* __restrict__ W3, const float* __restrict__ b3,
    float* __restrict__ f, float* __restrict__ g, float* __restrict__ h)
{
    int idx = blockIdx.x * 256 + threadIdx.x;   // < 18432*48 exactly
    int row = idx / 48;
    int col = idx - row * 48;
    const float* xr = x + (size_t)row * CCH;
    if (col < 8) {
        float acc = b1[col];
        #pragma unroll
        for (int k = 0; k < CCH; ++k) acc += xr[k] * W1[k * 8 + col];
        f[row * 8 + col] = acc;
    } else if (col < 16) {
        int c = col - 8;
        float acc = b2[c];
        #pragma unroll
        for (int k = 0; k < CCH; ++k) acc += xr[k] * W2[k * 8 + c];
        g[row * 8 + c] = acc * LOG2E;           // fold log2(e) for exp2 inner loop
    } else {
        int c = col - 16;
        float acc = b3[c];
        #pragma unroll
        for (int k = 0; k < CCH; ++k) acc += xr[k] * W3[k * 32 + c];
        h[row * 32 + c] = acc;
    }
}

// ---------------------------------------------------------------------------
// Kernel 2: attention, Q=2 register-blocked, NO LDS staging.
// f/h per key are read with wave-uniform addresses directly from global
// (compiler scalarizes to s_load; L2-resident stream). Each thread owns
// 2 queries (lane, lane+64) -> per-key data amortized over 128 dots/wave.
// Block = 4 waves over the SAME 128 queries, each wave 1/4 of the block's
// key split; partials merged via LDS ds_add, then one set of global
// atomics per block (split partials are directly summable: no max shift,
// scores bounded so exp2 cannot overflow).
// Grid: QG * KS = 144*8 = 1152 blocks.
// ---------------------------------------------------------------------------
__global__ __launch_bounds__(256) void attn_kernel(
    const float* __restrict__ f, const float* __restrict__ g,
    const float* __restrict__ h,
    float* __restrict__ l_acc, float* __restrict__ o_acc)
{
    __shared__ float red[128 * 33];   // [q][0]=l, [q][1..32]=o   (16.9 KB)

    int blk  = blockIdx.x;            // 0..1151
    int qg   = blk % QG;              // query group
    int ks   = blk / QG;              // key split 0..7
    int b    = qg / (QG / BATCH);     // batch
    int q0   = (qg % (QG / BATCH)) * 128;
    int wave = threadIdx.x >> 6;
    int lane = threadIdx.x & 63;

    // zero reduction buffer (visible to all after the post-loop barrier)
    for (int i = threadIdx.x; i < 128 * 33; i += 256) red[i] = 0.f;

    int rowA = b * NTOK + q0 + lane;
    int rowB = rowA + 64;
    const float4* gA = (const float4*)(g + (size_t)rowA * 8);
    const float4* gB = (const float4*)(g + (size_t)rowB * 8);
    float4 ga0 = gA[0], ga1 = gA[1];
    float4 gb0 = gB[0], gb1 = gB[1];

    float l0 = 0.f, l1 = 0.f;
    float acc0[DV], acc1[DV];
    #pragma unroll
    for (int v = 0; v < DV; ++v) { acc0[v] = 0.f; acc1[v] = 0.f; }

    int kstart = ks * KEYS_PER_BLOCK + wave * KEYS_PER_WAVE;  // uniform per wave
    const float* fk = f + ((size_t)b * NTOK + kstart) * 8;
    const float* hk = h + ((size_t)b * NTOK + kstart) * 32;

    #pragma unroll 2
    for (int j = 0; j < KEYS_PER_WAVE; ++j) {
        const float* fj = fk + j * 8;     // wave-uniform address
        const float* hj = hk + j * 32;    // wave-uniform address
        float f0 = fj[0], f1 = fj[1], f2 = fj[2], f3 = fj[3];
        float f4 = fj[4], f5 = fj[5], f6 = fj[6], f7 = fj[7];
        float s0 = f0*ga0.x + f1*ga0.y + f2*ga0.z + f3*ga0.w
                 + f4*ga1.x + f5*ga1.y + f6*ga1.z + f7*ga1.w;
        float s1 = f0*gb0.x + f1*gb0.y + f2*gb0.z + f3*gb0.w
                 + f4*gb1.x + f5*gb1.y + f6*gb1.z + f7*gb1.w;
        float p0 = __builtin_amdgcn_exp2f(s0);
        float p1 = __builtin_amdgcn_exp2f(s1);
        l0 += p0; l1 += p1;
        #pragma unroll
        for (int v = 0; v < DV; ++v) {
            float hv = hj[v];             // wave-uniform (SGPR) -> FMA s-operand
            acc0[v] += p0 * hv;
            acc1[v] += p1 * hv;
        }
    }

    __syncthreads();                      // zeros complete everywhere

    // cross-wave merge via LDS atomics (stride 33 -> 2-way bank alias = free)
    float* rA = red + lane * 33;
    float* rB = red + (lane + 64) * 33;
    atomicAdd(&rA[0], l0);
    atomicAdd(&rB[0], l1);
    #pragma unroll
    for (int v = 0; v < DV; ++v) {
        atomicAdd(&rA[1 + v], acc0[v]);
        atomicAdd(&rB[1 + v], acc1[v]);
    }
    __syncthreads();

    // one set of global atomics per block (KS=8 contenders per address)
    for (int i = threadIdx.x; i < 128 * 33; i += 256) {
        int qq = i / 33;
        int c  = i - qq * 33;
        float val = red[i];
        int row = b * NTOK + q0 + qq;
        if (c == 0) atomicAdd(&l_acc[row], val);
        else        atomicAdd(&o_acc[(size_t)row * DV + (c - 1)], val);
    }
}

// ---------------------------------------------------------------------------
// Kernel 3: normalize + output projection + residual.
// One wave per query (4 waves / 256-thread block).
//   o[k] = o_acc[row][k] / l_acc[row] ; out = gamma*(o@W4 + b4) + x
// ---------------------------------------------------------------------------
__global__ __launch_bounds__(256) void merge_kernel(
    const float* __restrict__ l_acc, const float* __restrict__ o_acc,
    const float* __restrict__ x,
    const float* __restrict__ W4, const float* __restrict__ b4,
    const float* __restrict__ gamma, float* __restrict__ out)
{
    __shared__ float oS[4][DV];
    int wave = threadIdx.x >> 6;
    int lane = threadIdx.x & 63;
    int row  = blockIdx.x * 4 + wave;     // < 18432 exactly

    float invL = 1.f / l_acc[row];
    if (lane < DV) {
        oS[wave][lane] = o_acc[(size_t)row * DV + lane] * invL;
    }
    __syncthreads();

    float dot = b4[lane];
    #pragma unroll
    for (int k = 0; k < DV; ++k) dot += oS[wave][k] * W4[k * 64 + lane];
    float gm  = gamma[0];
    float res = x[(size_t)row * 64 + lane];
    out[(size_t)row * 64 + lane] = gm * dot + res;
}

// ---------------------------------------------------------------------------
extern "C" void kernel_launch(void* const* d_in, const int* in_sizes, int n_in,
                              void* d_out, int out_size, void* d_ws, size_t ws_size,
                              hipStream_t stream) {
    const float* x     = (const float*)d_in[0];
    const float* W1    = (const float*)d_in[1];
    const float* b1    = (const float*)d_in[2];
    const float* W2    = (const float*)d_in[3];
    const float* b2    = (const float*)d_in[4];
    const float* W3    = (const float*)d_in[5];
    const float* b3    = (const float*)d_in[6];
    const float* W4    = (const float*)d_in[7];
    const float* b4    = (const float*)d_in[8];
    const float* gamma = (const float*)d_in[9];
    float* out = (float*)d_out;

    // Workspace layout (floats): total 1,492,992 floats = 5.97 MB
    float* ws = (float*)d_ws;
    float* f     = ws;                        // [0,       147456)
    float* g     = ws + 147456;               // [147456,  294912)
    float* h     = ws + 294912;               // [294912,  884736)
    float* l_acc = ws + 884736;               // [884736,  903168)
    float* o_acc = ws + 903168;               // [903168, 1492992)

    // zero l_acc + o_acc: 608256 floats = 152064 float4 -> 594 blocks
    zero_kernel<<<594, 256, 0, stream>>>((float4*)l_acc);

    // proj: 18432*48 threads
    proj_kernel<<<(ROWS * 48) / 256, 256, 0, stream>>>(
        x, W1, b1, W2, b2, W3, b3, f, g, h);

    // attention: 144 query-groups x 8 key-splits
    attn_kernel<<<QG * KS, 256, 0, stream>>>(f, g, h, l_acc, o_acc);

    // merge: 18432 queries / 4 waves per block
    merge_kernel<<<ROWS / 4, 256, 0, stream>>>(l_acc, o_acc, x, W4, b4, gamma, out);
}

// Round 5
// 245.893 us; speedup vs baseline: 2.8940x; 2.5039x over previous
//
#include <hip/hip_runtime.h>
#include <hip/hip_bf16.h>

// All reference dtypes are float32 (verified R3): inputs const float*, output float*.

#define BATCH 2
#define NTOK 9216        // 96*96
#define CCH 64
#define DK 8
#define DV 32
#define KS 4                          // key splits
#define KEYS_PER_BLOCK (NTOK / KS)    // 2304
#define KT 32                         // keys per MFMA tile
#define NKT (KEYS_PER_BLOCK / KT)     // 72 tiles
#define QTILES (18432 / 64)           // 288 query tiles (64 q per block)
#define LOG2E 1.44269504088896340736f
#define ROWS (BATCH * NTOK)           // 18432
#define PSTR 40                       // LDS p-buffer row stride in bf16 units

typedef __attribute__((ext_vector_type(8))) short bf16x8;   // 8 bf16 (4 VGPRs)
typedef __attribute__((ext_vector_type(4))) float f32x4;    // MFMA C/D

__device__ __forceinline__ short f2bf(float x) {
    __hip_bfloat16 h = __float2bfloat16(x);   // RNE
    return *(short*)&h;
}
__device__ __forceinline__ float bf2f(short s) {
    unsigned u = ((unsigned)(unsigned short)s) << 16;
    return *(float*)&u;
}

// ---------------------------------------------------------------------------
// Kernel 0: zero l_acc + o_acc: (18432 + 589824) floats = 152064 float4.
// ---------------------------------------------------------------------------
__global__ __launch_bounds__(256) void zero_kernel(float4* __restrict__ p) {
    int i = blockIdx.x * 256 + threadIdx.x;
    if (i < 152064) p[i] = make_float4(0.f, 0.f, 0.f, 0.f);
}

// ---------------------------------------------------------------------------
// Kernel 1: projections -> MFMA-ready bf16 operands.
//  gx[row][32]: [g_hi(8) | g_lo(8) | g_hi(8) | 0]   (g pre-scaled by log2e)
//  fx[key][32]: [f_hi(8) | f_hi(8) | f_lo(8) | 0]
//    K-slot pairing: g_hi*f_hi + g_lo*f_hi + g_hi*f_lo ~= fp32-exact g.f
//  hT[b][v][key]: bf16 transposed H for PV B-operand.
// ---------------------------------------------------------------------------
__global__ __launch_bounds__(256) void proj_kernel(
    const float* __restrict__ x,
    const float* __restrict__ W1, const float* __restrict__ b1,
    const float* __restrict__ W2, const float* __restrict__ b2,
    const float* __restrict__ W3, const float* __restrict__ b3,
    short* __restrict__ fx, short* __restrict__ gx, short* __restrict__ hT)
{
    int idx = blockIdx.x * 256 + threadIdx.x;   // < 18432*48 exactly
    int row = idx / 48;
    int col = idx - row * 48;
    const float* xr = x + (size_t)row * CCH;
    if (col < 8) {
        float acc = b1[col];
        #pragma unroll
        for (int k = 0; k < CCH; ++k) acc += xr[k] * W1[k * 8 + col];
        short hi = f2bf(acc);
        short lo = f2bf(acc - bf2f(hi));
        short* fr = fx + (size_t)row * 32;
        fr[col] = hi; fr[col + 8] = hi; fr[col + 16] = lo; fr[col + 24] = 0;
    } else if (col < 16) {
        int c = col - 8;
        float acc = b2[c];
        #pragma unroll
        for (int k = 0; k < CCH; ++k) acc += xr[k] * W2[k * 8 + c];
        acc *= LOG2E;                             // fold log2(e): exp2 inner loop
        short hi = f2bf(acc);
        short lo = f2bf(acc - bf2f(hi));
        short* gr = gx + (size_t)row * 32;
        gr[c] = hi; gr[c + 8] = lo; gr[c + 16] = hi; gr[c + 24] = 0;
    } else {
        int c = col - 16;
        float acc = b3[c];
        #pragma unroll
        for (int k = 0; k < CCH; ++k) acc += xr[k] * W3[k * 32 + c];
        int b = row / NTOK;
        int n = row - b * NTOK;
        hT[((size_t)(b * 32 + c)) * NTOK + n] = f2bf(acc);
    }
}

// ---------------------------------------------------------------------------
// Kernel 2: MFMA flash attention (no online max; scores bounded, exp2 safe).
// Block = 4 waves; wave w owns 16 queries. Per 32-key tile per wave:
//   2 QK MFMAs (16x16x32, hi/lo-packed K) -> S in C-layout (fp32)
//   exp2 -> bf16 -> LDS round-trip to A-layout (m120-verified transform)
//   2 PV MFMAs (v 0:16, 16:32) + 1 l-MFMA (B = ones) accumulate
// Split partials merged by global atomics (directly summable: no max shift).
// Grid: QTILES * KS = 288*4 = 1152 blocks.
// ---------------------------------------------------------------------------
__global__ __launch_bounds__(256) void attn_kernel(
    const short* __restrict__ fx, const short* __restrict__ gx,
    const short* __restrict__ hT,
    float* __restrict__ l_acc, float* __restrict__ o_acc)
{
    __shared__ short lds_p[4][16 * PSTR];     // per-wave 16q x 32k bf16 (+pad)

    const int tid  = threadIdx.x;
    const int wave = tid >> 6;
    const int lane = tid & 63;
    const int col  = lane & 15;               // MFMA n / C-col
    const int quad = lane >> 4;               // MFMA k-octet / C-row group

    const int blk = blockIdx.x;
    const int qt  = blk % QTILES;             // query tile 0..287
    const int ks  = blk / QTILES;             // key split 0..3
    const int b   = qt / (QTILES / BATCH);    // batch
    const int qq  = (qt % (QTILES / BATCH)) * 64;
    const int rowbase = b * NTOK + qq + wave * 16;

    // persistent A-operand: G-ext for this wave's 16 queries
    const bf16x8 ag = *(const bf16x8*)(gx + (size_t)(rowbase + col) * 32 + quad * 8);

    // all-ones B-frag (bf16 1.0 = 0x3F80) for l = P @ ones
    bf16x8 ones;
    #pragma unroll
    for (int j = 0; j < 8; ++j) ones[j] = (short)0x3F80;

    f32x4 o0 = {0.f, 0.f, 0.f, 0.f};
    f32x4 o1 = {0.f, 0.f, 0.f, 0.f};
    f32x4 lf = {0.f, 0.f, 0.f, 0.f};
    const f32x4 zero4 = {0.f, 0.f, 0.f, 0.f};

    short* lp = &lds_p[wave][0];
    const int kb0 = ks * KEYS_PER_BLOCK;
    const short* fbase = fx + ((size_t)b * NTOK + kb0) * 32;
    const short* hbase0 = hT + ((size_t)(b * 32) + col) * NTOK + kb0;       // v = col
    const short* hbase1 = hT + ((size_t)(b * 32) + 16 + col) * NTOK + kb0; // v = 16+col

    #pragma unroll 2
    for (int t = 0; t < NKT; ++t) {
        const int kb = t * KT;
        // B-frags for QK: keys kb..kb+15 and kb+16..kb+31
        bf16x8 bf0 = *(const bf16x8*)(fbase + (size_t)(kb + col) * 32 + quad * 8);
        bf16x8 bf1 = *(const bf16x8*)(fbase + (size_t)(kb + 16 + col) * 32 + quad * 8);
        // B-frags for PV: hT[v][kb + quad*8 + j]
        bf16x8 hb0 = *(const bf16x8*)(hbase0 + kb + quad * 8);
        bf16x8 hb1 = *(const bf16x8*)(hbase1 + kb + quad * 8);

        f32x4 s0 = __builtin_amdgcn_mfma_f32_16x16x32_bf16(ag, bf0, zero4, 0, 0, 0);
        f32x4 s1 = __builtin_amdgcn_mfma_f32_16x16x32_bf16(ag, bf1, zero4, 0, 0, 0);

        // exp2 -> bf16 -> LDS[q][k]  (C-layout: q = quad*4+r, k = n*16+col)
        #pragma unroll
        for (int r = 0; r < 4; ++r) {
            lp[(quad * 4 + r) * PSTR + col]      = f2bf(__builtin_amdgcn_exp2f(s0[r]));
            lp[(quad * 4 + r) * PSTR + 16 + col] = f2bf(__builtin_amdgcn_exp2f(s1[r]));
        }
        // A-layout read-back: lane (m=col, k=quad*8+j)
        bf16x8 pf = *(const bf16x8*)(lp + col * PSTR + quad * 8);

        o0 = __builtin_amdgcn_mfma_f32_16x16x32_bf16(pf, hb0, o0, 0, 0, 0);
        o1 = __builtin_amdgcn_mfma_f32_16x16x32_bf16(pf, hb1, o1, 0, 0, 0);
        lf = __builtin_amdgcn_mfma_f32_16x16x32_bf16(pf, ones, lf, 0, 0, 0);
    }

    // merge: C-layout row = quad*4+r (query), col = v (o0: v=col, o1: v=16+col)
    #pragma unroll
    for (int r = 0; r < 4; ++r) {
        int grow = rowbase + quad * 4 + r;
        atomicAdd(&o_acc[(size_t)grow * 32 + col],      o0[r]);
        atomicAdd(&o_acc[(size_t)grow * 32 + 16 + col], o1[r]);
    }
    if (col == 0) {
        #pragma unroll
        for (int r = 0; r < 4; ++r)
            atomicAdd(&l_acc[rowbase + quad * 4 + r], lf[r]);
    }
}

// ---------------------------------------------------------------------------
// Kernel 3: normalize + output projection + residual (fp32 weights).
// One wave per query: o[k] = o_acc/l ; out = gamma*(o@W4 + b4) + x
// ---------------------------------------------------------------------------
__global__ __launch_bounds__(256) void merge_kernel(
    const float* __restrict__ l_acc, const float* __restrict__ o_acc,
    const float* __restrict__ x,
    const float* __restrict__ W4, const float* __restrict__ b4,
    const float* __restrict__ gamma, float* __restrict__ out)
{
    __shared__ float oS[4][DV];
    int wave = threadIdx.x >> 6;
    int lane = threadIdx.x & 63;
    int row  = blockIdx.x * 4 + wave;     // < 18432 exactly

    float invL = 1.f / l_acc[row];
    if (lane < DV) {
        oS[wave][lane] = o_acc[(size_t)row * DV + lane] * invL;
    }
    __syncthreads();

    float dot = b4[lane];
    #pragma unroll
    for (int k = 0; k < DV; ++k) dot += oS[wave][k] * W4[k * 64 + lane];
    float gm  = gamma[0];
    float res = x[(size_t)row * 64 + lane];
    out[(size_t)row * 64 + lane] = gm * dot + res;
}

// ---------------------------------------------------------------------------
extern "C" void kernel_launch(void* const* d_in, const int* in_sizes, int n_in,
                              void* d_out, int out_size, void* d_ws, size_t ws_size,
                              hipStream_t stream) {
    const float* x     = (const float*)d_in[0];
    const float* W1    = (const float*)d_in[1];
    const float* b1    = (const float*)d_in[2];
    const float* W2    = (const float*)d_in[3];
    const float* b2    = (const float*)d_in[4];
    const float* W3    = (const float*)d_in[5];
    const float* b3    = (const float*)d_in[6];
    const float* W4    = (const float*)d_in[7];
    const float* b4    = (const float*)d_in[8];
    const float* gamma = (const float*)d_in[9];
    float* out = (float*)d_out;

    // Workspace: fx/gx/hT bf16 (1.18 MB each) + l_acc + o_acc = 5.97 MB total
    short* fx    = (short*)d_ws;                  // 589824 shorts
    short* gx    = fx + (size_t)ROWS * 32;        // 589824 shorts
    short* hT    = gx + (size_t)ROWS * 32;        // 589824 shorts
    float* l_acc = (float*)(hT + (size_t)ROWS * 32);   // 18432 floats
    float* o_acc = l_acc + ROWS;                  // 589824 floats

    // zero l_acc + o_acc: 608256 floats = 152064 float4 -> 594 blocks
    zero_kernel<<<594, 256, 0, stream>>>((float4*)l_acc);

    // proj: 18432*48 threads
    proj_kernel<<<(ROWS * 48) / 256, 256, 0, stream>>>(
        x, W1, b1, W2, b2, W3, b3, fx, gx, hT);

    // attention: 288 query-tiles x 4 key-splits = 1152 blocks
    attn_kernel<<<QTILES * KS, 256, 0, stream>>>(fx, gx, hT, l_acc, o_acc);

    // merge: 18432 queries / 4 waves per block
    merge_kernel<<<ROWS / 4, 256, 0, stream>>>(l_acc, o_acc, x, W4, b4, gamma, out);
}

// Round 6
// 177.644 us; speedup vs baseline: 4.0058x; 1.3842x over previous
//
#include <hip/hip_runtime.h>
#include <hip/hip_bf16.h>

// All reference dtypes are float32 (verified R3): inputs const float*, output float*.

#define BATCH 2
#define NTOK 9216        // 96*96
#define CCH 64
#define DV 32
#define KS 4                          // key splits (per block; x2 waves -> eff 8)
#define KEYS_PER_BLOCK (NTOK / KS)    // 2304
#define KEYS_PER_WAVE (KEYS_PER_BLOCK / 2)  // 1152
#define KT 32                         // keys per MFMA tile
#define NKT (KEYS_PER_WAVE / KT)      // 36 tiles per wave
#define ROWS (BATCH * NTOK)           // 18432
#define QT (ROWS / 32)                // 576 query tiles (32 q per block)
#define LOG2E 1.44269504088896340736f
#define PROW 20                       // LDS p-row stride in dwords (16B-aligned, 2-way banks)

typedef __attribute__((ext_vector_type(8))) short bf16x8;   // 8 bf16 (4 VGPRs)
typedef __attribute__((ext_vector_type(4))) float f32x4;    // MFMA C/D

__device__ __forceinline__ short f2bf(float x) {
    __hip_bfloat16 h = __float2bfloat16(x);   // RNE
    return *(short*)&h;
}
__device__ __forceinline__ float bf2f(short s) {
    unsigned u = ((unsigned)(unsigned short)s) << 16;
    return *(float*)&u;
}

// ---------------------------------------------------------------------------
// Kernel 0: zero l_acc + o_acc: (18432 + 589824) floats = 152064 float4.
// ---------------------------------------------------------------------------
__global__ __launch_bounds__(256) void zero_kernel(float4* __restrict__ p) {
    int i = blockIdx.x * 256 + threadIdx.x;
    if (i < 152064) p[i] = make_float4(0.f, 0.f, 0.f, 0.f);
}

// ---------------------------------------------------------------------------
// Kernel 1: projections -> MFMA-ready bf16 operands.
//  gx[row][32]: [g_hi(8) | g_lo(8) | g_hi(8) | 0]   (g pre-scaled by log2e)
//  fx[key][32]: [f_hi(8) | f_hi(8) | f_lo(8) | 0]
//  hT[b][v][key']: bf16 transposed H, with keys PERMUTED within each 32-key
//   tile: k' = 2*(k&15) + ((k>>4)&1) — matches the packed-P LDS layout in
//   attn (P(kcol),P(kcol+16) packed into one dword). MFMA sums over k, so a
//   consistent permutation of A's k and B's k is exact.
// ---------------------------------------------------------------------------
__global__ __launch_bounds__(256) void proj_kernel(
    const float* __restrict__ x,
    const float* __restrict__ W1, const float* __restrict__ b1,
    const float* __restrict__ W2, const float* __restrict__ b2,
    const float* __restrict__ W3, const float* __restrict__ b3,
    short* __restrict__ fx, short* __restrict__ gx, short* __restrict__ hT)
{
    int idx = blockIdx.x * 256 + threadIdx.x;   // < 18432*48 exactly
    int row = idx / 48;
    int col = idx - row * 48;

    // x row via vector loads
    const float4* x4 = (const float4*)(x + (size_t)row * CCH);
    float4 xv[16];
    #pragma unroll
    for (int i = 0; i < 16; ++i) xv[i] = x4[i];
    const float* xr = (const float*)xv;

    if (col < 8) {
        float acc = b1[col];
        #pragma unroll
        for (int k = 0; k < CCH; ++k) acc += xr[k] * W1[k * 8 + col];
        short hi = f2bf(acc);
        short lo = f2bf(acc - bf2f(hi));
        short* fr = fx + (size_t)row * 32;
        fr[col] = hi; fr[col + 8] = hi; fr[col + 16] = lo; fr[col + 24] = 0;
    } else if (col < 16) {
        int c = col - 8;
        float acc = b2[c];
        #pragma unroll
        for (int k = 0; k < CCH; ++k) acc += xr[k] * W2[k * 8 + c];
        acc *= LOG2E;                             // fold log2(e): exp2 inner loop
        short hi = f2bf(acc);
        short lo = f2bf(acc - bf2f(hi));
        short* gr = gx + (size_t)row * 32;
        gr[c] = hi; gr[c + 8] = lo; gr[c + 16] = hi; gr[c + 24] = 0;
    } else {
        int c = col - 16;
        float acc = b3[c];
        #pragma unroll
        for (int k = 0; k < CCH; ++k) acc += xr[k] * W3[k * 32 + c];
        int b  = row / NTOK;
        int n  = row - b * NTOK;
        int ni = n & 31;
        int np = (n & ~31) | (2 * (ni & 15) + (ni >> 4));   // k' permutation
        hT[(size_t)(b * 32 + c) * NTOK + np] = f2bf(acc);
    }
}

// ---------------------------------------------------------------------------
// Kernel 2: MFMA flash attention. Block = 2 waves over the SAME 32 queries,
// each wave half the block's key split (eff. 8-way key split). Per 32-key
// tile per wave: 4 QK MFMA -> 16 exp2 -> pack 2 bf16/dword (k'-perm) ->
// 8 ds_write_b32 (2-way banks = free) -> 2 ds_read_b128 (16B aligned) ->
// 4 PV MFMA + 2 l-MFMA (ones). Next tile's 4 B-frags prefetched.
// Cross-wave merge in LDS, then one set of global atomics (wave 0).
// Grid: QT * KS = 576*4 = 2304 blocks = exactly 9 per CU.
// ---------------------------------------------------------------------------
__global__ __launch_bounds__(128) void attn_kernel(
    const short* __restrict__ fx, const short* __restrict__ gx,
    const short* __restrict__ hT,
    float* __restrict__ l_acc, float* __restrict__ o_acc)
{
    __shared__ __attribute__((aligned(16))) int lds_p[2][32 * PROW]; // 2x2560B
    __shared__ float red[32 * 33];                                   // 4224B

    const int tid  = threadIdx.x;
    const int wave = tid >> 6;
    const int lane = tid & 63;
    const int col  = lane & 15;               // MFMA n / C-col
    const int quad = lane >> 4;               // MFMA k-octet / C-row group

    const int blk = blockIdx.x;
    const int qt  = blk % QT;                 // query tile 0..575
    const int ks  = blk / QT;                 // key split 0..3
    const int b   = qt / (QT / BATCH);        // batch
    const int qbase   = (qt % (QT / BATCH)) * 32;
    const int rowbase = b * NTOK + qbase;

    // persistent A-operands: G-ext for 2 query sub-tiles (q 0..15, 16..31)
    const bf16x8 agA = *(const bf16x8*)(gx + (size_t)(rowbase + col) * 32 + quad * 8);
    const bf16x8 agB = *(const bf16x8*)(gx + (size_t)(rowbase + 16 + col) * 32 + quad * 8);

    bf16x8 ones;
    #pragma unroll
    for (int j = 0; j < 8; ++j) ones[j] = (short)0x3F80;   // bf16 1.0

    f32x4 oA0 = {0.f,0.f,0.f,0.f}, oA1 = {0.f,0.f,0.f,0.f};
    f32x4 oB0 = {0.f,0.f,0.f,0.f}, oB1 = {0.f,0.f,0.f,0.f};
    f32x4 lA  = {0.f,0.f,0.f,0.f}, lB  = {0.f,0.f,0.f,0.f};
    const f32x4 zero4 = {0.f,0.f,0.f,0.f};

    int* lp = &lds_p[wave][0];
    const int kstart = ks * KEYS_PER_BLOCK + wave * KEYS_PER_WAVE;
    const short* fbase = fx + ((size_t)b * NTOK + kstart) * 32;
    const short* hp0 = hT + ((size_t)(b * 32 + col)) * NTOK + kstart;       // v=col
    const short* hp1 = hT + ((size_t)(b * 32 + 16 + col)) * NTOK + kstart;  // v=16+col

    // preload tile 0
    bf16x8 bf0 = *(const bf16x8*)(fbase + (size_t)col * 32 + quad * 8);
    bf16x8 bf1 = *(const bf16x8*)(fbase + (size_t)(16 + col) * 32 + quad * 8);
    bf16x8 hb0 = *(const bf16x8*)(hp0 + quad * 8);
    bf16x8 hb1 = *(const bf16x8*)(hp1 + quad * 8);

    for (int t = 0; t < NKT; ++t) {
        // prefetch next tile's B-frags (clamped re-load on last iter)
        const int kn = (t + 1 < NKT) ? (t + 1) * KT : t * KT;
        bf16x8 nf0 = *(const bf16x8*)(fbase + (size_t)(kn + col) * 32 + quad * 8);
        bf16x8 nf1 = *(const bf16x8*)(fbase + (size_t)(kn + 16 + col) * 32 + quad * 8);
        bf16x8 nh0 = *(const bf16x8*)(hp0 + kn + quad * 8);
        bf16x8 nh1 = *(const bf16x8*)(hp1 + kn + quad * 8);

        f32x4 sA0 = __builtin_amdgcn_mfma_f32_16x16x32_bf16(agA, bf0, zero4, 0, 0, 0);
        f32x4 sA1 = __builtin_amdgcn_mfma_f32_16x16x32_bf16(agA, bf1, zero4, 0, 0, 0);
        f32x4 sB0 = __builtin_amdgcn_mfma_f32_16x16x32_bf16(agB, bf0, zero4, 0, 0, 0);
        f32x4 sB1 = __builtin_amdgcn_mfma_f32_16x16x32_bf16(agB, bf1, zero4, 0, 0, 0);

        // exp2 -> round -> pack two bf16 (k'=2col, 2col+1) -> one b32 write
        #pragma unroll
        for (int r = 0; r < 4; ++r) {
            unsigned a0 = (unsigned)__float_as_int(__builtin_amdgcn_exp2f(sA0[r])) + 0x8000u;
            unsigned a1 = (unsigned)__float_as_int(__builtin_amdgcn_exp2f(sA1[r])) + 0x8000u;
            lp[(quad * 4 + r) * PROW + col] =
                (int)__builtin_amdgcn_perm(a1, a0, 0x07060302u);
            unsigned c0 = (unsigned)__float_as_int(__builtin_amdgcn_exp2f(sB0[r])) + 0x8000u;
            unsigned c1 = (unsigned)__float_as_int(__builtin_amdgcn_exp2f(sB1[r])) + 0x8000u;
            lp[(16 + quad * 4 + r) * PROW + col] =
                (int)__builtin_amdgcn_perm(c1, c0, 0x07060302u);
        }
        // A-layout read-back (16B aligned: PROW*4=80B rows, quad*16B)
        bf16x8 pfA = *(const bf16x8*)(lp + col * PROW + quad * 4);
        bf16x8 pfB = *(const bf16x8*)(lp + (16 + col) * PROW + quad * 4);

        oA0 = __builtin_amdgcn_mfma_f32_16x16x32_bf16(pfA, hb0, oA0, 0, 0, 0);
        oA1 = __builtin_amdgcn_mfma_f32_16x16x32_bf16(pfA, hb1, oA1, 0, 0, 0);
        oB0 = __builtin_amdgcn_mfma_f32_16x16x32_bf16(pfB, hb0, oB0, 0, 0, 0);
        oB1 = __builtin_amdgcn_mfma_f32_16x16x32_bf16(pfB, hb1, oB1, 0, 0, 0);
        lA  = __builtin_amdgcn_mfma_f32_16x16x32_bf16(pfA, ones, lA, 0, 0, 0);
        lB  = __builtin_amdgcn_mfma_f32_16x16x32_bf16(pfB, ones, lB, 0, 0, 0);

        bf0 = nf0; bf1 = nf1; hb0 = nh0; hb1 = nh1;
    }

    // cross-wave merge: wave1 stores, wave0 adds + global atomics
    if (wave == 1) {
        #pragma unroll
        for (int r = 0; r < 4; ++r) {
            red[(quad * 4 + r) * 33 + col]           = oA0[r];
            red[(quad * 4 + r) * 33 + 16 + col]      = oA1[r];
            red[(16 + quad * 4 + r) * 33 + col]      = oB0[r];
            red[(16 + quad * 4 + r) * 33 + 16 + col] = oB1[r];
        }
        if (col == 0) {
            #pragma unroll
            for (int r = 0; r < 4; ++r) {
                red[(quad * 4 + r) * 33 + 32]      = lA[r];
                red[(16 + quad * 4 + r) * 33 + 32] = lB[r];
            }
        }
    }
    __syncthreads();
    if (wave == 0) {
        #pragma unroll
        for (int r = 0; r < 4; ++r) {
            int qA = quad * 4 + r, qB = 16 + quad * 4 + r;
            atomicAdd(&o_acc[(size_t)(rowbase + qA) * 32 + col],      oA0[r] + red[qA * 33 + col]);
            atomicAdd(&o_acc[(size_t)(rowbase + qA) * 32 + 16 + col], oA1[r] + red[qA * 33 + 16 + col]);
            atomicAdd(&o_acc[(size_t)(rowbase + qB) * 32 + col],      oB0[r] + red[qB * 33 + col]);
            atomicAdd(&o_acc[(size_t)(rowbase + qB) * 32 + 16 + col], oB1[r] + red[qB * 33 + 16 + col]);
        }
        if (col == 0) {
            #pragma unroll
            for (int r = 0; r < 4; ++r) {
                int qA = quad * 4 + r, qB = 16 + quad * 4 + r;
                atomicAdd(&l_acc[rowbase + qA], lA[r] + red[qA * 33 + 32]);
                atomicAdd(&l_acc[rowbase + qB], lB[r] + red[qB * 33 + 32]);
            }
        }
    }
}

// ---------------------------------------------------------------------------
// Kernel 3: normalize + output projection + residual (fp32 weights).
// One wave per query: o[k] = o_acc/l ; out = gamma*(o@W4 + b4) + x
// ---------------------------------------------------------------------------
__global__ __launch_bounds__(256) void merge_kernel(
    const float* __restrict__ l_acc, const float* __restrict__ o_acc,
    const float* __restrict__ x,
    const float* __restrict__ W4, const float* __restrict__ b4,
    const float* __restrict__ gamma, float* __restrict__ out)
{
    __shared__ float oS[4][DV];
    int wave = threadIdx.x >> 6;
    int lane = threadIdx.x & 63;
    int row  = blockIdx.x * 4 + wave;     // < 18432 exactly

    float invL = 1.f / l_acc[row];
    if (lane < DV) {
        oS[wave][lane] = o_acc[(size_t)row * DV + lane] * invL;
    }
    __syncthreads();

    float dot = b4[lane];
    #pragma unroll
    for (int k = 0; k < DV; ++k) dot += oS[wave][k] * W4[k * 64 + lane];
    float gm  = gamma[0];
    float res = x[(size_t)row * 64 + lane];
    out[(size_t)row * 64 + lane] = gm * dot + res;
}

// ---------------------------------------------------------------------------
extern "C" void kernel_launch(void* const* d_in, const int* in_sizes, int n_in,
                              void* d_out, int out_size, void* d_ws, size_t ws_size,
                              hipStream_t stream) {
    const float* x     = (const float*)d_in[0];
    const float* W1    = (const float*)d_in[1];
    const float* b1    = (const float*)d_in[2];
    const float* W2    = (const float*)d_in[3];
    const float* b2    = (const float*)d_in[4];
    const float* W3    = (const float*)d_in[5];
    const float* b3    = (const float*)d_in[6];
    const float* W4    = (const float*)d_in[7];
    const float* b4    = (const float*)d_in[8];
    const float* gamma = (const float*)d_in[9];
    float* out = (float*)d_out;

    // Workspace: fx/gx/hT bf16 (1.18 MB each) + l_acc + o_acc = 5.97 MB total
    short* fx    = (short*)d_ws;                  // 589824 shorts
    short* gx    = fx + (size_t)ROWS * 32;        // 589824 shorts
    short* hT    = gx + (size_t)ROWS * 32;        // 589824 shorts
    float* l_acc = (float*)(hT + (size_t)ROWS * 32);   // 18432 floats
    float* o_acc = l_acc + ROWS;                  // 589824 floats

    // zero l_acc + o_acc: 608256 floats = 152064 float4 -> 594 blocks
    zero_kernel<<<594, 256, 0, stream>>>((float4*)l_acc);

    // proj: 18432*48 threads
    proj_kernel<<<(ROWS * 48) / 256, 256, 0, stream>>>(
        x, W1, b1, W2, b2, W3, b3, fx, gx, hT);

    // attention: 576 query-tiles x 4 key-splits = 2304 blocks (9/CU exact)
    attn_kernel<<<QT * KS, 128, 0, stream>>>(fx, gx, hT, l_acc, o_acc);

    // merge: 18432 queries / 4 waves per block
    merge_kernel<<<ROWS / 4, 256, 0, stream>>>(l_acc, o_acc, x, W4, b4, gamma, out);
}

// Round 7
// 172.988 us; speedup vs baseline: 4.1137x; 1.0269x over previous
//
#include <hip/hip_runtime.h>
#include <hip/hip_bf16.h>

// All reference dtypes are float32 (verified R3): inputs const float*, output float*.

#define BATCH 2
#define NTOK 9216        // 96*96
#define CCH 64
#define DV 32
#define KS 8                          // key splits (per block; x2 waves -> eff 16)
#define KEYS_PER_BLOCK (NTOK / KS)    // 1152
#define KEYS_PER_WAVE (KEYS_PER_BLOCK / 2)  // 576
#define KT 32                         // keys per MFMA tile
#define NKT (KEYS_PER_WAVE / KT)      // 18 tiles per wave
#define ROWS (BATCH * NTOK)           // 18432
#define QT (ROWS / 32)                // 576 query tiles (32 q per block)
#define LOG2E 1.44269504088896340736f
#define PROW 20                       // LDS p-row stride in dwords (16B-aligned, 2-way banks)
#define PB 32                         // proj rows per block

typedef __attribute__((ext_vector_type(8))) short bf16x8;   // 8 bf16 (4 VGPRs)
typedef __attribute__((ext_vector_type(4))) float f32x4;    // MFMA C/D

__device__ __forceinline__ short f2bf(float x) {
    __hip_bfloat16 h = __float2bfloat16(x);   // RNE
    return *(short*)&h;
}
__device__ __forceinline__ float bf2f(short s) {
    unsigned u = ((unsigned)(unsigned short)s) << 16;
    return *(float*)&u;
}

// ---------------------------------------------------------------------------
// Kernel 0: zero l_acc + o_acc: (18432 + 589824) floats = 152064 float4.
// ---------------------------------------------------------------------------
__global__ __launch_bounds__(256) void zero_kernel(float4* __restrict__ p) {
    int i = blockIdx.x * 256 + threadIdx.x;
    if (i < 152064) p[i] = make_float4(0.f, 0.f, 0.f, 0.f);
}

// ---------------------------------------------------------------------------
// Kernel 1: projections -> MFMA-ready bf16 operands, fully-coalesced writes.
// Block = 512 threads per 32 rows. x staged once in LDS (broadcast reads);
// outputs staged in LDS then written as contiguous dwords:
//  gx[row][32]: [g_hi(8) | g_lo(8) | g_hi(8) | 0]   (g pre-scaled by log2e)
//  fx[key][32]: [f_hi(8) | f_hi(8) | f_lo(8) | 0]
//  hT[b][v][key']: transposed H, keys permuted per 32-tile:
//   k' = 2*(k&15) + (k>>4)  — matches attn's packed-P dword layout.
// ---------------------------------------------------------------------------
__global__ __launch_bounds__(512) void proj_kernel(
    const float* __restrict__ x,
    const float* __restrict__ W1, const float* __restrict__ b1,
    const float* __restrict__ W2, const float* __restrict__ b2,
    const float* __restrict__ W3, const float* __restrict__ b3,
    short* __restrict__ fx, short* __restrict__ gx, short* __restrict__ hT)
{
    __shared__ float xS[PB][CCH];        // 8 KB
    __shared__ short fgS[2][PB][32];     // 4 KB staging for fx, gx
    __shared__ short hS[32][PB + 2];     // 2.1 KB staging for hT (padded banks)

    const int tid = threadIdx.x;
    const int r0  = blockIdx.x * PB;     // 32-row tile, batch-aligned (9216%32==0)

    // cooperative x load: 512 threads x float4 = 32 rows x 64 floats
    ((float4*)xS)[tid] = ((const float4*)(x + (size_t)r0 * CCH))[tid];
    __syncthreads();

    // phase 1: f/g — thread (rr = tid>>4, c = tid&15)
    {
        const int rr = tid >> 4;
        const int c  = tid & 15;
        const float* xr = xS[rr];
        if (c < 8) {
            float acc = b1[c];
            #pragma unroll
            for (int k = 0; k < CCH; ++k) acc += xr[k] * W1[k * 8 + c];
            short hi = f2bf(acc);
            short lo = f2bf(acc - bf2f(hi));
            fgS[0][rr][c] = hi; fgS[0][rr][c + 8] = hi;
            fgS[0][rr][c + 16] = lo; fgS[0][rr][c + 24] = 0;
        } else {
            const int cc = c - 8;
            float acc = b2[cc];
            #pragma unroll
            for (int k = 0; k < CCH; ++k) acc += xr[k] * W2[k * 8 + cc];
            acc *= LOG2E;                 // fold log2(e) for exp2 inner loop
            short hi = f2bf(acc);
            short lo = f2bf(acc - bf2f(hi));
            fgS[1][rr][cc] = hi; fgS[1][rr][cc + 8] = lo;
            fgS[1][rr][cc + 16] = hi; fgS[1][rr][cc + 24] = 0;
        }
    }
    // phase 2: h — thread (c = tid&31, rbase = tid>>5) covers rows rbase, rbase+16
    {
        const int c = tid & 31;
        const int rbase = tid >> 5;
        #pragma unroll
        for (int s = 0; s < 2; ++s) {
            int rr = rbase + s * 16;
            float acc = b3[c];
            #pragma unroll
            for (int k = 0; k < CCH; ++k) acc += xS[rr][k] * W3[k * 32 + c];
            int np = 2 * (rr & 15) + (rr >> 4);   // k' permutation within tile
            hS[c][np] = f2bf(acc);
        }
    }
    __syncthreads();

    // coalesced write-out (dwords)
    ((int*)(fx + (size_t)r0 * 32))[tid] = ((const int*)fgS[0])[tid];
    ((int*)(gx + (size_t)r0 * 32))[tid] = ((const int*)fgS[1])[tid];
    {
        const int b  = r0 / NTOK;
        const int n0 = r0 - b * NTOK;
        const int c  = tid >> 4;
        const int d  = tid & 15;
        ((int*)(hT + (size_t)(b * 32 + c) * NTOK + n0))[d] = ((const int*)&hS[c][0])[d];
    }
}

// ---------------------------------------------------------------------------
// Kernel 2: MFMA flash attention, software-pipelined.
// Block = 2 waves over the SAME 32 queries, each wave half the key split.
// Per 32-key tile: pack S(t) (16 exp2 -> 8 ds_write_b32) -> prefetch frags(t+1)
// -> 2 ds_read_b128 -> 6 PV/l MFMA (tile t) -> 4 QK MFMA (tile t+1).
// red[] overlays lds_p[] (lifetimes separated by __syncthreads).
// Grid: QT * KS = 576*8 = 4608 blocks (18/CU).
// ---------------------------------------------------------------------------
__global__ __launch_bounds__(128) void attn_kernel(
    const short* __restrict__ fx, const short* __restrict__ gx,
    const short* __restrict__ hT,
    float* __restrict__ l_acc, float* __restrict__ o_acc)
{
    __shared__ __attribute__((aligned(16))) char ldsbuf[5120]; // lds_p / red overlay

    const int tid  = threadIdx.x;
    const int wave = tid >> 6;
    const int lane = tid & 63;
    const int col  = lane & 15;               // MFMA n / C-col
    const int quad = lane >> 4;               // MFMA k-octet / C-row group

    const int blk = blockIdx.x;
    const int qt  = blk % QT;                 // query tile 0..575
    const int ks  = blk / QT;                 // key split 0..7
    const int b   = qt / (QT / BATCH);        // batch
    const int qbase   = (qt % (QT / BATCH)) * 32;
    const int rowbase = b * NTOK + qbase;

    // persistent A-operands: G-ext for 2 query sub-tiles (q 0..15, 16..31)
    const bf16x8 agA = *(const bf16x8*)(gx + (size_t)(rowbase + col) * 32 + quad * 8);
    const bf16x8 agB = *(const bf16x8*)(gx + (size_t)(rowbase + 16 + col) * 32 + quad * 8);

    bf16x8 ones;
    #pragma unroll
    for (int j = 0; j < 8; ++j) ones[j] = (short)0x3F80;   // bf16 1.0

    f32x4 oA0 = {0.f,0.f,0.f,0.f}, oA1 = {0.f,0.f,0.f,0.f};
    f32x4 oB0 = {0.f,0.f,0.f,0.f}, oB1 = {0.f,0.f,0.f,0.f};
    f32x4 lA  = {0.f,0.f,0.f,0.f}, lB  = {0.f,0.f,0.f,0.f};
    const f32x4 zero4 = {0.f,0.f,0.f,0.f};

    int* lp = (int*)ldsbuf + wave * (32 * PROW);
    const int kstart = ks * KEYS_PER_BLOCK + wave * KEYS_PER_WAVE;
    const short* fbase = fx + ((size_t)b * NTOK + kstart) * 32;
    const short* hp0 = hT + ((size_t)(b * 32 + col)) * NTOK + kstart;       // v=col
    const short* hp1 = hT + ((size_t)(b * 32 + 16 + col)) * NTOK + kstart;  // v=16+col

    // preload tile 0 frags + QK(0)
    bf16x8 bf0 = *(const bf16x8*)(fbase + (size_t)col * 32 + quad * 8);
    bf16x8 bf1 = *(const bf16x8*)(fbase + (size_t)(16 + col) * 32 + quad * 8);
    bf16x8 hb0 = *(const bf16x8*)(hp0 + quad * 8);
    bf16x8 hb1 = *(const bf16x8*)(hp1 + quad * 8);

    f32x4 sA0 = __builtin_amdgcn_mfma_f32_16x16x32_bf16(agA, bf0, zero4, 0, 0, 0);
    f32x4 sA1 = __builtin_amdgcn_mfma_f32_16x16x32_bf16(agA, bf1, zero4, 0, 0, 0);
    f32x4 sB0 = __builtin_amdgcn_mfma_f32_16x16x32_bf16(agB, bf0, zero4, 0, 0, 0);
    f32x4 sB1 = __builtin_amdgcn_mfma_f32_16x16x32_bf16(agB, bf1, zero4, 0, 0, 0);

    for (int t = 0; t < NKT; ++t) {
        // pack S(t): exp2 -> +0x8000 (RN-ish) -> perm two bf16 into one dword
        #pragma unroll
        for (int r = 0; r < 4; ++r) {
            unsigned a0 = (unsigned)__float_as_int(__builtin_amdgcn_exp2f(sA0[r])) + 0x8000u;
            unsigned a1 = (unsigned)__float_as_int(__builtin_amdgcn_exp2f(sA1[r])) + 0x8000u;
            lp[(quad * 4 + r) * PROW + col] =
                (int)__builtin_amdgcn_perm(a1, a0, 0x07060302u);
            unsigned c0 = (unsigned)__float_as_int(__builtin_amdgcn_exp2f(sB0[r])) + 0x8000u;
            unsigned c1 = (unsigned)__float_as_int(__builtin_amdgcn_exp2f(sB1[r])) + 0x8000u;
            lp[(16 + quad * 4 + r) * PROW + col] =
                (int)__builtin_amdgcn_perm(c1, c0, 0x07060302u);
        }

        // prefetch frags for tile t+1 (clamped to 0 on last iter; discarded)
        const int kn = (t + 1 < NKT) ? (t + 1) * KT : 0;
        bf16x8 nf0 = *(const bf16x8*)(fbase + (size_t)(kn + col) * 32 + quad * 8);
        bf16x8 nf1 = *(const bf16x8*)(fbase + (size_t)(kn + 16 + col) * 32 + quad * 8);
        bf16x8 nh0 = *(const bf16x8*)(hp0 + kn + quad * 8);
        bf16x8 nh1 = *(const bf16x8*)(hp1 + kn + quad * 8);

        // A-layout read-back (16B aligned rows of 80B)
        bf16x8 pfA = *(const bf16x8*)(lp + col * PROW + quad * 4);
        bf16x8 pfB = *(const bf16x8*)(lp + (16 + col) * PROW + quad * 4);

        // PV + l for tile t (h-frags belong to tile t)
        oA0 = __builtin_amdgcn_mfma_f32_16x16x32_bf16(pfA, hb0, oA0, 0, 0, 0);
        oA1 = __builtin_amdgcn_mfma_f32_16x16x32_bf16(pfA, hb1, oA1, 0, 0, 0);
        oB0 = __builtin_amdgcn_mfma_f32_16x16x32_bf16(pfB, hb0, oB0, 0, 0, 0);
        oB1 = __builtin_amdgcn_mfma_f32_16x16x32_bf16(pfB, hb1, oB1, 0, 0, 0);
        lA  = __builtin_amdgcn_mfma_f32_16x16x32_bf16(pfA, ones, lA, 0, 0, 0);
        lB  = __builtin_amdgcn_mfma_f32_16x16x32_bf16(pfB, ones, lB, 0, 0, 0);

        // QK for tile t+1 (independent of the PV chain above)
        sA0 = __builtin_amdgcn_mfma_f32_16x16x32_bf16(agA, nf0, zero4, 0, 0, 0);
        sA1 = __builtin_amdgcn_mfma_f32_16x16x32_bf16(agA, nf1, zero4, 0, 0, 0);
        sB0 = __builtin_amdgcn_mfma_f32_16x16x32_bf16(agB, nf0, zero4, 0, 0, 0);
        sB1 = __builtin_amdgcn_mfma_f32_16x16x32_bf16(agB, nf1, zero4, 0, 0, 0);
        hb0 = nh0; hb1 = nh1;
    }

    // cross-wave merge: wave1 stores to red (overlays lds_p; barrier separates)
    __syncthreads();
    float* red = (float*)ldsbuf;          // 32*33 floats = 4224 B <= 5120 B
    if (wave == 1) {
        #pragma unroll
        for (int r = 0; r < 4; ++r) {
            red[(quad * 4 + r) * 33 + col]           = oA0[r];
            red[(quad * 4 + r) * 33 + 16 + col]      = oA1[r];
            red[(16 + quad * 4 + r) * 33 + col]      = oB0[r];
            red[(16 + quad * 4 + r) * 33 + 16 + col] = oB1[r];
        }
        if (col == 0) {
            #pragma unroll
            for (int r = 0; r < 4; ++r) {
                red[(quad * 4 + r) * 33 + 32]      = lA[r];
                red[(16 + quad * 4 + r) * 33 + 32] = lB[r];
            }
        }
    }
    __syncthreads();
    if (wave == 0) {
        #pragma unroll
        for (int r = 0; r < 4; ++r) {
            int qA = quad * 4 + r, qB = 16 + quad * 4 + r;
            atomicAdd(&o_acc[(size_t)(rowbase + qA) * 32 + col],      oA0[r] + red[qA * 33 + col]);
            atomicAdd(&o_acc[(size_t)(rowbase + qA) * 32 + 16 + col], oA1[r] + red[qA * 33 + 16 + col]);
            atomicAdd(&o_acc[(size_t)(rowbase + qB) * 32 + col],      oB0[r] + red[qB * 33 + col]);
            atomicAdd(&o_acc[(size_t)(rowbase + qB) * 32 + 16 + col], oB1[r] + red[qB * 33 + 16 + col]);
        }
        if (col == 0) {
            #pragma unroll
            for (int r = 0; r < 4; ++r) {
                int qA = quad * 4 + r, qB = 16 + quad * 4 + r;
                atomicAdd(&l_acc[rowbase + qA], lA[r] + red[qA * 33 + 32]);
                atomicAdd(&l_acc[rowbase + qB], lB[r] + red[qB * 33 + 32]);
            }
        }
    }
}

// ---------------------------------------------------------------------------
// Kernel 3: normalize + output projection + residual (fp32 weights).
// One wave per query: o[k] = o_acc/l ; out = gamma*(o@W4 + b4) + x
// ---------------------------------------------------------------------------
__global__ __launch_bounds__(256) void merge_kernel(
    const float* __restrict__ l_acc, const float* __restrict__ o_acc,
    const float* __restrict__ x,
    const float* __restrict__ W4, const float* __restrict__ b4,
    const float* __restrict__ gamma, float* __restrict__ out)
{
    __shared__ float oS[4][DV];
    int wave = threadIdx.x >> 6;
    int lane = threadIdx.x & 63;
    int row  = blockIdx.x * 4 + wave;     // < 18432 exactly

    float invL = 1.f / l_acc[row];
    if (lane < DV) {
        oS[wave][lane] = o_acc[(size_t)row * DV + lane] * invL;
    }
    __syncthreads();

    float dot = b4[lane];
    #pragma unroll
    for (int k = 0; k < DV; ++k) dot += oS[wave][k] * W4[k * 64 + lane];
    float gm  = gamma[0];
    float res = x[(size_t)row * 64 + lane];
    out[(size_t)row * 64 + lane] = gm * dot + res;
}

// ---------------------------------------------------------------------------
extern "C" void kernel_launch(void* const* d_in, const int* in_sizes, int n_in,
                              void* d_out, int out_size, void* d_ws, size_t ws_size,
                              hipStream_t stream) {
    const float* x     = (const float*)d_in[0];
    const float* W1    = (const float*)d_in[1];
    const float* b1    = (const float*)d_in[2];
    const float* W2    = (const float*)d_in[3];
    const float* b2    = (const float*)d_in[4];
    const float* W3    = (const float*)d_in[5];
    const float* b3    = (const float*)d_in[6];
    const float* W4    = (const float*)d_in[7];
    const float* b4    = (const float*)d_in[8];
    const float* gamma = (const float*)d_in[9];
    float* out = (float*)d_out;

    // Workspace: fx/gx/hT bf16 (1.18 MB each) + l_acc + o_acc = 5.97 MB total
    short* fx    = (short*)d_ws;                  // 589824 shorts
    short* gx    = fx + (size_t)ROWS * 32;        // 589824 shorts
    short* hT    = gx + (size_t)ROWS * 32;        // 589824 shorts
    float* l_acc = (float*)(hT + (size_t)ROWS * 32);   // 18432 floats
    float* o_acc = l_acc + ROWS;                  // 589824 floats

    // zero l_acc + o_acc: 608256 floats = 152064 float4 -> 594 blocks
    zero_kernel<<<594, 256, 0, stream>>>((float4*)l_acc);

    // proj: 576 blocks x 512 threads (32 rows each)
    proj_kernel<<<ROWS / PB, 512, 0, stream>>>(
        x, W1, b1, W2, b2, W3, b3, fx, gx, hT);

    // attention: 576 query-tiles x 8 key-splits = 4608 blocks (18/CU)
    attn_kernel<<<QT * KS, 128, 0, stream>>>(fx, gx, hT, l_acc, o_acc);

    // merge: 18432 queries / 4 waves per block
    merge_kernel<<<ROWS / 4, 256, 0, stream>>>(l_acc, o_acc, x, W4, b4, gamma, out);
}

// Round 8
// 154.926 us; speedup vs baseline: 4.5932x; 1.1166x over previous
//
#include <hip/hip_runtime.h>
#include <hip/hip_bf16.h>

// All reference dtypes are float32 (verified R3): inputs const float*, output float*.

#define BATCH 2
#define NTOK 9216        // 96*96
#define CCH 64
#define DV 32
#define KS 4                          // key splits (per block; x2 waves -> eff 8)
#define KEYS_PER_BLOCK (NTOK / KS)    // 2304
#define KEYS_PER_WAVE (KEYS_PER_BLOCK / 2)  // 1152
#define KT 32                         // keys per MFMA tile
#define NKT (KEYS_PER_WAVE / KT)      // 36 tiles per wave
#define ROWS (BATCH * NTOK)           // 18432
#define QT (ROWS / 32)                // 576 query tiles (32 q per block)
#define LOG2E 1.44269504088896340736f
#define PB 32                         // proj rows per block

typedef __attribute__((ext_vector_type(8))) short bf16x8;   // 8 bf16 (4 VGPRs)
typedef __attribute__((ext_vector_type(4))) float f32x4;    // MFMA C/D

__device__ __forceinline__ short f2bf(float x) {
    __hip_bfloat16 h = __float2bfloat16(x);   // RNE
    return *(short*)&h;
}
__device__ __forceinline__ float bf2f(short s) {
    unsigned u = ((unsigned)(unsigned short)s) << 16;
    return *(float*)&u;
}

// ---------------------------------------------------------------------------
// Kernel 1: projections -> MFMA-ready bf16 operands + zeroing of l/o_acc
// (folded in; proj completes before attn by stream order).
//  gx[row][32]: [g_hi(8) | g_lo(8) | g_hi(8) | 0]   (g pre-scaled by log2e)
//  fx[key][32]: [f_hi(8) | f_hi(8) | f_lo(8) | 0]
//  hT[b][v][k_pv]: transposed H with keys permuted within each 32-key tile:
//   PV k-dim slot p = quad*8+j holds phys key (j<4 ? 4*quad+j : 16+4*quad+j-4)
//   -> inverse: np(ni) = ((ni&15)>>2)*8 + (ni&3) + ((ni>>4)&1)*4.
//   This makes the post-exp2 P registers directly usable as the PV A-frag.
// ---------------------------------------------------------------------------
__global__ __launch_bounds__(512) void proj_kernel(
    const float* __restrict__ x,
    const float* __restrict__ W1, const float* __restrict__ b1,
    const float* __restrict__ W2, const float* __restrict__ b2,
    const float* __restrict__ W3, const float* __restrict__ b3,
    short* __restrict__ fx, short* __restrict__ gx, short* __restrict__ hT,
    float4* __restrict__ zbase)
{
    __shared__ float xS[PB][CCH];        // 8 KB
    __shared__ short fgS[2][PB][32];     // 4 KB staging for fx, gx
    __shared__ short hS[32][PB + 2];     // 2.1 KB staging for hT

    const int tid = threadIdx.x;
    const int r0  = blockIdx.x * PB;     // 32-row tile, batch-aligned

    // zero slice of l_acc + o_acc: 152064 float4 total / 576 blocks = 264
    if (tid < 264) zbase[blockIdx.x * 264 + tid] = make_float4(0.f, 0.f, 0.f, 0.f);

    // cooperative x load: 512 threads x float4 = 32 rows x 64 floats
    ((float4*)xS)[tid] = ((const float4*)(x + (size_t)r0 * CCH))[tid];
    __syncthreads();

    // phase 1: f/g — thread (rr = tid>>4, c = tid&15)
    {
        const int rr = tid >> 4;
        const int c  = tid & 15;
        const float* xr = xS[rr];
        if (c < 8) {
            float acc = b1[c];
            #pragma unroll
            for (int k = 0; k < CCH; ++k) acc += xr[k] * W1[k * 8 + c];
            short hi = f2bf(acc);
            short lo = f2bf(acc - bf2f(hi));
            fgS[0][rr][c] = hi; fgS[0][rr][c + 8] = hi;
            fgS[0][rr][c + 16] = lo; fgS[0][rr][c + 24] = 0;
        } else {
            const int cc = c - 8;
            float acc = b2[cc];
            #pragma unroll
            for (int k = 0; k < CCH; ++k) acc += xr[k] * W2[k * 8 + cc];
            acc *= LOG2E;                 // fold log2(e) for exp2 inner loop
            short hi = f2bf(acc);
            short lo = f2bf(acc - bf2f(hi));
            fgS[1][rr][cc] = hi; fgS[1][rr][cc + 8] = lo;
            fgS[1][rr][cc + 16] = hi; fgS[1][rr][cc + 24] = 0;
        }
    }
    // phase 2: h — thread (c = tid&31, rbase = tid>>5) covers rows rbase, rbase+16
    {
        const int c = tid & 31;
        const int rbase = tid >> 5;
        #pragma unroll
        for (int s = 0; s < 2; ++s) {
            int rr = rbase + s * 16;
            float acc = b3[c];
            #pragma unroll
            for (int k = 0; k < CCH; ++k) acc += xS[rr][k] * W3[k * 32 + c];
            int np = ((rr & 15) >> 2) * 8 + (rr & 3) + ((rr >> 4) & 1) * 4;
            hS[c][np] = f2bf(acc);
        }
    }
    __syncthreads();

    // coalesced write-out (dwords)
    ((int*)(fx + (size_t)r0 * 32))[tid] = ((const int*)fgS[0])[tid];
    ((int*)(gx + (size_t)r0 * 32))[tid] = ((const int*)fgS[1])[tid];
    {
        const int b  = r0 / NTOK;
        const int n0 = r0 - b * NTOK;
        const int c  = tid >> 4;
        const int d  = tid & 15;
        ((int*)(hT + (size_t)(b * 32 + c) * NTOK + n0))[d] = ((const int*)&hS[c][0])[d];
    }
}

// ---------------------------------------------------------------------------
// Kernel 2: MFMA flash attention with ZERO in-loop LDS.
// QK computed transposed (A=f-ext, B=g-ext): lane holds S[q=col][k=quad*4+r]
// per 16-key MFMA. After exp2, each lane's 8 P values (two 16-key chunks)
// are EXACTLY the A-frag of the PV 16x16x32 MFMA under the hT key
// permutation — no LDS round-trip, no cross-lane movement.
// l accumulated per-lane, reduced cross-quad via shfl_xor at the end.
// Block = 2 waves over the SAME 32 queries, each wave half the key split.
// Grid: QT * KS = 576*4 = 2304 blocks (9/CU exact).
// ---------------------------------------------------------------------------
__global__ __launch_bounds__(128, 4) void attn_kernel(
    const short* __restrict__ fx, const short* __restrict__ gx,
    const short* __restrict__ hT,
    float* __restrict__ l_acc, float* __restrict__ o_acc)
{
    __shared__ float red[32 * 33];            // epilogue-only, 4224 B

    const int tid  = threadIdx.x;
    const int wave = tid >> 6;
    const int lane = tid & 63;
    const int col  = lane & 15;
    const int quad = lane >> 4;

    const int blk = blockIdx.x;
    const int qt  = blk % QT;                 // query tile 0..575
    const int ks  = blk / QT;                 // key split 0..3
    const int b   = qt / (QT / BATCH);        // batch
    const int qbase   = (qt % (QT / BATCH)) * 32;
    const int rowbase = b * NTOK + qbase;

    // persistent B-operands for QK: g-ext for 2 query sub-tiles
    const bf16x8 agA = *(const bf16x8*)(gx + (size_t)(rowbase + col) * 32 + quad * 8);
    const bf16x8 agB = *(const bf16x8*)(gx + (size_t)(rowbase + 16 + col) * 32 + quad * 8);

    f32x4 oA0 = {0.f,0.f,0.f,0.f}, oA1 = {0.f,0.f,0.f,0.f};
    f32x4 oB0 = {0.f,0.f,0.f,0.f}, oB1 = {0.f,0.f,0.f,0.f};
    float lA = 0.f, lB = 0.f;
    const f32x4 zero4 = {0.f,0.f,0.f,0.f};

    const int kstart = ks * KEYS_PER_BLOCK + wave * KEYS_PER_WAVE;
    const short* fbase = fx + ((size_t)b * NTOK + kstart) * 32;
    const short* hp0 = hT + ((size_t)(b * 32 + col)) * NTOK + kstart;       // v=col
    const short* hp1 = hT + ((size_t)(b * 32 + 16 + col)) * NTOK + kstart;  // v=16+col

    // preload tile 0
    bf16x8 fa0 = *(const bf16x8*)(fbase + (size_t)col * 32 + quad * 8);        // keys 0-15
    bf16x8 fa1 = *(const bf16x8*)(fbase + (size_t)(16 + col) * 32 + quad * 8); // keys 16-31
    bf16x8 hb0 = *(const bf16x8*)(hp0 + quad * 8);   // v=col,    k_pv=quad*8..+7
    bf16x8 hb1 = *(const bf16x8*)(hp1 + quad * 8);   // v=16+col

    union PU { int i[4]; bf16x8 v; };

    for (int t = 0; t < NKT; ++t) {
        // QK transposed: D[k][q] -> lane holds S[q=col][k=quad*4+r]
        f32x4 t00 = __builtin_amdgcn_mfma_f32_16x16x32_bf16(fa0, agA, zero4, 0, 0, 0);
        f32x4 t01 = __builtin_amdgcn_mfma_f32_16x16x32_bf16(fa1, agA, zero4, 0, 0, 0);
        f32x4 t10 = __builtin_amdgcn_mfma_f32_16x16x32_bf16(fa0, agB, zero4, 0, 0, 0);
        f32x4 t11 = __builtin_amdgcn_mfma_f32_16x16x32_bf16(fa1, agB, zero4, 0, 0, 0);

        // prefetch tile t+1 (clamped; discarded on last iter)
        const int kn = (t + 1 < NKT) ? (t + 1) * KT : 0;
        bf16x8 nf0 = *(const bf16x8*)(fbase + (size_t)(kn + col) * 32 + quad * 8);
        bf16x8 nf1 = *(const bf16x8*)(fbase + (size_t)(kn + 16 + col) * 32 + quad * 8);
        bf16x8 nh0 = *(const bf16x8*)(hp0 + kn + quad * 8);
        bf16x8 nh1 = *(const bf16x8*)(hp1 + kn + quad * 8);

        // exp2 + round-to-bf16 + pack: P registers ARE the PV A-frag
        PU pA, pB;
        {
            float e0 = __builtin_amdgcn_exp2f(t00[0]), e1 = __builtin_amdgcn_exp2f(t00[1]);
            float e2 = __builtin_amdgcn_exp2f(t00[2]), e3 = __builtin_amdgcn_exp2f(t00[3]);
            float e4 = __builtin_amdgcn_exp2f(t01[0]), e5 = __builtin_amdgcn_exp2f(t01[1]);
            float e6 = __builtin_amdgcn_exp2f(t01[2]), e7 = __builtin_amdgcn_exp2f(t01[3]);
            lA += (e0 + e1) + (e2 + e3) + (e4 + e5) + (e6 + e7);
            pA.i[0] = (int)__builtin_amdgcn_perm((unsigned)__float_as_int(e1) + 0x8000u,
                                                 (unsigned)__float_as_int(e0) + 0x8000u, 0x07060302u);
            pA.i[1] = (int)__builtin_amdgcn_perm((unsigned)__float_as_int(e3) + 0x8000u,
                                                 (unsigned)__float_as_int(e2) + 0x8000u, 0x07060302u);
            pA.i[2] = (int)__builtin_amdgcn_perm((unsigned)__float_as_int(e5) + 0x8000u,
                                                 (unsigned)__float_as_int(e4) + 0x8000u, 0x07060302u);
            pA.i[3] = (int)__builtin_amdgcn_perm((unsigned)__float_as_int(e7) + 0x8000u,
                                                 (unsigned)__float_as_int(e6) + 0x8000u, 0x07060302u);
        }
        {
            float e0 = __builtin_amdgcn_exp2f(t10[0]), e1 = __builtin_amdgcn_exp2f(t10[1]);
            float e2 = __builtin_amdgcn_exp2f(t10[2]), e3 = __builtin_amdgcn_exp2f(t10[3]);
            float e4 = __builtin_amdgcn_exp2f(t11[0]), e5 = __builtin_amdgcn_exp2f(t11[1]);
            float e6 = __builtin_amdgcn_exp2f(t11[2]), e7 = __builtin_amdgcn_exp2f(t11[3]);
            lB += (e0 + e1) + (e2 + e3) + (e4 + e5) + (e6 + e7);
            pB.i[0] = (int)__builtin_amdgcn_perm((unsigned)__float_as_int(e1) + 0x8000u,
                                                 (unsigned)__float_as_int(e0) + 0x8000u, 0x07060302u);
            pB.i[1] = (int)__builtin_amdgcn_perm((unsigned)__float_as_int(e3) + 0x8000u,
                                                 (unsigned)__float_as_int(e2) + 0x8000u, 0x07060302u);
            pB.i[2] = (int)__builtin_amdgcn_perm((unsigned)__float_as_int(e5) + 0x8000u,
                                                 (unsigned)__float_as_int(e4) + 0x8000u, 0x07060302u);
            pB.i[3] = (int)__builtin_amdgcn_perm((unsigned)__float_as_int(e7) + 0x8000u,
                                                 (unsigned)__float_as_int(e6) + 0x8000u, 0x07060302u);
        }

        // PV: A = packed P (direct), B = permuted hT frags
        oA0 = __builtin_amdgcn_mfma_f32_16x16x32_bf16(pA.v, hb0, oA0, 0, 0, 0);
        oA1 = __builtin_amdgcn_mfma_f32_16x16x32_bf16(pA.v, hb1, oA1, 0, 0, 0);
        oB0 = __builtin_amdgcn_mfma_f32_16x16x32_bf16(pB.v, hb0, oB0, 0, 0, 0);
        oB1 = __builtin_amdgcn_mfma_f32_16x16x32_bf16(pB.v, hb1, oB1, 0, 0, 0);

        fa0 = nf0; fa1 = nf1; hb0 = nh0; hb1 = nh1;
    }

    // l: reduce across quads (lanes col, col+16, col+32, col+48 share q=col)
    lA += __shfl_xor(lA, 16); lA += __shfl_xor(lA, 32);
    lB += __shfl_xor(lB, 16); lB += __shfl_xor(lB, 32);

    // cross-wave merge: wave1 stores to red, wave0 combines + global atomics.
    // O layout: lane holds O[q=quad*4+r][v=col] (oX0) / [v=16+col] (oX1).
    if (wave == 1) {
        #pragma unroll
        for (int r = 0; r < 4; ++r) {
            red[(quad * 4 + r) * 33 + col]           = oA0[r];
            red[(quad * 4 + r) * 33 + 16 + col]      = oA1[r];
            red[(16 + quad * 4 + r) * 33 + col]      = oB0[r];
            red[(16 + quad * 4 + r) * 33 + 16 + col] = oB1[r];
        }
        if (quad == 0) {
            red[col * 33 + 32]        = lA;
            red[(16 + col) * 33 + 32] = lB;
        }
    }
    __syncthreads();
    if (wave == 0) {
        #pragma unroll
        for (int r = 0; r < 4; ++r) {
            int qA = quad * 4 + r, qB = 16 + quad * 4 + r;
            atomicAdd(&o_acc[(size_t)(rowbase + qA) * 32 + col],      oA0[r] + red[qA * 33 + col]);
            atomicAdd(&o_acc[(size_t)(rowbase + qA) * 32 + 16 + col], oA1[r] + red[qA * 33 + 16 + col]);
            atomicAdd(&o_acc[(size_t)(rowbase + qB) * 32 + col],      oB0[r] + red[qB * 33 + col]);
            atomicAdd(&o_acc[(size_t)(rowbase + qB) * 32 + 16 + col], oB1[r] + red[qB * 33 + 16 + col]);
        }
        if (quad == 0) {
            atomicAdd(&l_acc[rowbase + col],      lA + red[col * 33 + 32]);
            atomicAdd(&l_acc[rowbase + 16 + col], lB + red[(16 + col) * 33 + 32]);
        }
    }
}

// ---------------------------------------------------------------------------
// Kernel 3: normalize + output projection + residual (fp32 weights).
// One wave per query: o[k] = o_acc/l ; out = gamma*(o@W4 + b4) + x
// ---------------------------------------------------------------------------
__global__ __launch_bounds__(256) void merge_kernel(
    const float* __restrict__ l_acc, const float* __restrict__ o_acc,
    const float* __restrict__ x,
    const float* __restrict__ W4, const float* __restrict__ b4,
    const float* __restrict__ gamma, float* __restrict__ out)
{
    __shared__ float oS[4][DV];
    int wave = threadIdx.x >> 6;
    int lane = threadIdx.x & 63;
    int row  = blockIdx.x * 4 + wave;     // < 18432 exactly

    float invL = 1.f / l_acc[row];
    if (lane < DV) {
        oS[wave][lane] = o_acc[(size_t)row * DV + lane] * invL;
    }
    __syncthreads();

    float dot = b4[lane];
    #pragma unroll
    for (int k = 0; k < DV; ++k) dot += oS[wave][k] * W4[k * 64 + lane];
    float gm  = gamma[0];
    float res = x[(size_t)row * 64 + lane];
    out[(size_t)row * 64 + lane] = gm * dot + res;
}

// ---------------------------------------------------------------------------
extern "C" void kernel_launch(void* const* d_in, const int* in_sizes, int n_in,
                              void* d_out, int out_size, void* d_ws, size_t ws_size,
                              hipStream_t stream) {
    const float* x     = (const float*)d_in[0];
    const float* W1    = (const float*)d_in[1];
    const float* b1    = (const float*)d_in[2];
    const float* W2    = (const float*)d_in[3];
    const float* b2    = (const float*)d_in[4];
    const float* W3    = (const float*)d_in[5];
    const float* b3    = (const float*)d_in[6];
    const float* W4    = (const float*)d_in[7];
    const float* b4    = (const float*)d_in[8];
    const float* gamma = (const float*)d_in[9];
    float* out = (float*)d_out;

    // Workspace: fx/gx/hT bf16 (1.18 MB each) + l_acc + o_acc = 5.97 MB total
    short* fx    = (short*)d_ws;                  // 589824 shorts
    short* gx    = fx + (size_t)ROWS * 32;        // 589824 shorts
    short* hT    = gx + (size_t)ROWS * 32;        // 589824 shorts
    float* l_acc = (float*)(hT + (size_t)ROWS * 32);   // 18432 floats
    float* o_acc = l_acc + ROWS;                  // 589824 floats

    // proj (+ zeroing of l_acc/o_acc): 576 blocks x 512 threads
    proj_kernel<<<ROWS / PB, 512, 0, stream>>>(
        x, W1, b1, W2, b2, W3, b3, fx, gx, hT, (float4*)l_acc);

    // attention: 576 query-tiles x 4 key-splits = 2304 blocks (9/CU exact)
    attn_kernel<<<QT * KS, 128, 0, stream>>>(fx, gx, hT, l_acc, o_acc);

    // merge: 18432 queries / 4 waves per block
    merge_kernel<<<ROWS / 4, 256, 0, stream>>>(l_acc, o_acc, x, W4, b4, gamma, out);
}